// Round 11
// baseline (240.250 us; speedup 1.0000x reference)
//
#include <hip/hip_runtime.h>
#include <math.h>

#define B 8
#define S 2048
#define D_MODEL 512
#define NK 256      // n_kernels (conv out channels / attention feature dim)
#define KSZ 9
#define NC 4096     // n_classes
#define PADW 4
#define SSPLIT 4    // attention s-dimension split
#define CM 32       // conv s-rows per block (r11: 64->32, grid 256->512 = 2 blk/CU)
#define CW (CM + 8) // staged window rows (40)
#define NSTG (KSZ * 16)                // 144 K-stages: stg = t*16 + h (h = 32-d chunk)
#define NTILES ((S / SSPLIT) / 32)     // 16 x-tiles per attn block

typedef __attribute__((ext_vector_type(8))) short bf16x8;
typedef __attribute__((ext_vector_type(4))) float f32x4;
typedef __attribute__((ext_vector_type(16))) float f32x16;

static __device__ __forceinline__ unsigned short f2bf(float f) {
    unsigned int u = __float_as_uint(f);
    unsigned int r = (u + 0x7fffu + ((u >> 16) & 1u)) >> 16;
    return (unsigned short)r;
}

#define GLOAD_LDS16(g, l) __builtin_amdgcn_global_load_lds( \
    (const __attribute__((address_space(1))) void*)(g),     \
    (__attribute__((address_space(3))) void*)(l), 16, 0, 0)

// ---- fused prep: conv_w -> wtb [stg][k][d32] bf16 (stage-contig 16KB);
// ---- U (pre-scaled by log2e) / F fp32 -> bf16, 4 elems/thread vectorized --
#define PREP_W (KSZ * NK * D_MODEL)
#define PREP_UF (NC * NK)
#define PREP_N (PREP_W + (2 * PREP_UF) / 4)
__global__ __launch_bounds__(256) void prep_all(
    const float* __restrict__ w, unsigned short* __restrict__ wtb,
    const float* __restrict__ U, unsigned short* __restrict__ Ub,
    const float* __restrict__ F, unsigned short* __restrict__ Fb)
{
    const float LOG2E = 1.44269504088896340736f;
    int idx = blockIdx.x * 256 + threadIdx.x;
    if (idx < PREP_W) {
        int dd  = idx & 31;
        int k   = (idx >> 5) & (NK - 1);
        int stg = idx >> 13;              // / (32*NK)
        int t = stg >> 4, h = stg & 15;
        wtb[idx] = f2bf(w[((size_t)k * D_MODEL + h * 32 + dd) * KSZ + t]);
        return;
    }
    idx -= PREP_W;
    if (idx < PREP_UF / 4) {
        float4 v = ((const float4*)U)[idx];
        ushort4 o;
        o.x = f2bf(v.x * LOG2E); o.y = f2bf(v.y * LOG2E);
        o.z = f2bf(v.z * LOG2E); o.w = f2bf(v.w * LOG2E);
        ((ushort4*)Ub)[idx] = o;
        return;
    }
    idx -= PREP_UF / 4;
    if (idx < PREP_UF / 4) {
        float4 v = ((const float4*)F)[idx];
        ushort4 o;
        o.x = f2bf(v.x); o.y = f2bf(v.y);
        o.z = f2bf(v.z); o.w = f2bf(v.w);
        ((ushort4*)Fb)[idx] = o;
    }
}

// ---- embed-gather + MFMA conv1d + bias + tanh -> xf bf16 [b][s][k] --------
// r11: CM 64->32. Old grid = 256 blocks = EXACTLY 1 block/CU: the serial
// embed-gather staging phase (HBM-latency) and the K-loop (L2-latency B
// stream, 2 waves/SIMD) never overlapped across blocks; every barrier
// stalled the whole CU. Now 512 blocks, 40KB LDS, lb(512,4) => 2 blocks/CU:
// one block's K-loop covers the other's staging, K-loop TLP = 4 waves/SIMD.
// A-buffers halve (2 reads/stage), VGPR est ~110 <= 128 cap.
// (Depth-3 pipeline, stage-contiguous weight stream unchanged — r8-proven.)
__global__ __launch_bounds__(512, 4) void conv_mfma(
    const int* __restrict__ text, const float* __restrict__ emb,
    const unsigned short* __restrict__ wtb, const float* __restrict__ bias,
    unsigned short* __restrict__ xf)
{
    __shared__ unsigned short xs[CW * D_MODEL];   // 40,960 B
    const int b  = blockIdx.x >> 6;               // S/CM = 64 s-blocks
    const int s0 = (blockIdx.x & 63) * CM;
    const int tid = threadIdx.x;

    for (int u = tid; u < CW * 64; u += 512) {    // 2560 units = 5 iters
        int row = u >> 6, c = u & 63;             // c = logical 16B chunk
        int gs = s0 + row - PADW;
        float4 v0 = make_float4(0.f, 0.f, 0.f, 0.f), v1 = v0;
        if (gs >= 0 && gs < S) {
            int tok = text[b * S + gs];
            const float4* e4 = (const float4*)(emb + (size_t)tok * D_MODEL + c * 8);
            v0 = e4[0]; v1 = e4[1];
        }
        union { bf16x8 v; unsigned short us[8]; } pk;
        pk.us[0] = f2bf(v0.x); pk.us[1] = f2bf(v0.y);
        pk.us[2] = f2bf(v0.z); pk.us[3] = f2bf(v0.w);
        pk.us[4] = f2bf(v1.x); pk.us[5] = f2bf(v1.y);
        pk.us[6] = f2bf(v1.z); pk.us[7] = f2bf(v1.w);
        int phys = c ^ (row & 7);
        *(bf16x8*)(xs + row * D_MODEL + phys * 8) = pk.v;
    }
    __syncthreads();                              // the ONLY barrier

    const int wv   = tid >> 6;                    // 0..7
    const int lane = tid & 63;
    const int cl   = lane & 15;
    const int quad = lane >> 4;
    const int n0   = wv * 32;                     // 8 waves cover 256 channels

    bf16x8 A0[2], A1[2], A2[2], B0[2], B1[2], B2[2];
    f32x4 acc[2][2] = {};

    #define LDB(BB, stg)                                                      \
        {                                                                     \
            const unsigned short* wp = wtb + (size_t)(stg) * (NK * 32)        \
                                       + (n0 + cl) * 32 + quad * 8;           \
            BB[0] = *(const bf16x8*)(wp);                                     \
            BB[1] = *(const bf16x8*)(wp + 16 * 32);                           \
        }
    #define LDA(AA, stg)                                                      \
        {                                                                     \
            int t_ = (stg) >> 4, h_ = (stg) & 15;                             \
            _Pragma("unroll")                                                 \
            for (int ms = 0; ms < 2; ms++) {                                  \
                int row = cl + ms * 16 + t_;                                  \
                int ph  = (h_ * 4 + quad) ^ (row & 7);                        \
                AA[ms] = *(const bf16x8*)(xs + row * D_MODEL + ph * 8);       \
            }                                                                 \
        }
    #define FENCE asm volatile("" ::: "memory");
    #define DOMFMA(AA, BB)                                                    \
        _Pragma("unroll")                                                     \
        for (int ms = 0; ms < 2; ms++) {                                      \
            acc[ms][0] = __builtin_amdgcn_mfma_f32_16x16x32_bf16(AA[ms], BB[0], acc[ms][0], 0, 0, 0); \
            acc[ms][1] = __builtin_amdgcn_mfma_f32_16x16x32_bf16(AA[ms], BB[1], acc[ms][1], 0, 0, 0); \
        }

    LDB(B0, 0) LDA(A0, 0) LDB(B1, 1) LDA(A1, 1) LDB(B2, 2) LDA(A2, 2) FENCE

    for (int ss = 0; ss < NSTG; ss += 3) {        // 48 iters
        DOMFMA(A0, B0)
        if (ss + 3 < NSTG) { LDB(B0, ss + 3) LDA(A0, ss + 3) FENCE }
        DOMFMA(A1, B1)
        if (ss + 4 < NSTG) { LDB(B1, ss + 4) LDA(A1, ss + 4) FENCE }
        DOMFMA(A2, B2)
        if (ss + 5 < NSTG) { LDB(B2, ss + 5) LDA(A2, ss + 5) FENCE }
    }

    #pragma unroll
    for (int ns = 0; ns < 2; ns++) {
        const int k = n0 + ns * 16 + cl;
        const float bk = bias[k];
        #pragma unroll
        for (int ms = 0; ms < 2; ms++) {
            #pragma unroll
            for (int r = 0; r < 4; r++) {
                int s = s0 + ms * 16 + quad * 4 + r;
                float v = acc[ms][ns][r] + bk;
                float e = __expf(2.f * v);
                float th = 1.f - 2.f / (e + 1.f); // tanh(v)
                xf[((size_t)b * S + s) * NK + k] = f2bf(th);
            }
        }
    }
}

// -------- MFMA attention: max-free softmax, bf16 U/F tables ----------------
// r10 result: 32x32x16 halved bank conflicts (8.4M->4.2M) and VALU (25->17)
// but dur flat at ~68us = 40% of dense peak — the documented plateau for
// non-8-phase structures. attn considered locally converged; kept as-is.
#define WAITVM4 asm volatile("s_waitcnt vmcnt(4)" ::: "memory")
#define WAITVM0 asm volatile("s_waitcnt vmcnt(0)" ::: "memory")
__global__ __launch_bounds__(256, 2) void attn_mfma(
    const unsigned short* __restrict__ xf, const unsigned short* __restrict__ Ub,
    const unsigned short* __restrict__ Fb, float* __restrict__ pl,
    float* __restrict__ pg)
{
    __shared__ unsigned short xsa[3 * 32 * NK];   // 3 x 16 KB
    const int b    = blockIdx.z;
    const int sp   = blockIdx.y;
    const int tid  = threadIdx.x;
    const int wv   = tid >> 6;
    const int lane = tid & 63;
    const int row  = lane & 31;                   // A s-row / B class row
    const int bh   = lane >> 5;                   // k-half selector
    const int c0   = blockIdx.x * 128 + wv * 32;  // 32 classes per wave
    const int wvu  = __builtin_amdgcn_readfirstlane(wv);

    // B tables: class = lane&31, k = bh*8 + kk*16 .. +8  (16 slices)
    bf16x8 uf[16], ff[16];
    {
        const unsigned short* up = Ub + (size_t)(c0 + row) * NK + bh * 8;
        const unsigned short* fp = Fb + (size_t)(c0 + row) * NK + bh * 8;
        #pragma unroll
        for (int kk = 0; kk < 16; kk++) {
            uf[kk] = *(const bf16x8*)(up + kk * 16);
            ff[kk] = *(const bf16x8*)(fp + kk * 16);
        }
    }

    const int sbeg = sp * (S / SSPLIT);
    const unsigned short* xb = xf + ((size_t)b * S + sbeg) * NK;

    // hoisted staging pointers (loop-invariant; only t*32*NK varies)
    const unsigned short* ssrc[4];
    unsigned short* sdst[4];
    #pragma unroll
    for (int j = 0; j < 4; j++) {
        int C = j * 256 + tid;
        int r = C >> 5, p = C & 31;
        int jl = p ^ (r & 7);
        ssrc[j] = xb + (size_t)r * NK + jl * 8;
        sdst[j] = xsa + j * 2048 + wvu * 512;
    }

    #define STAGE(bb, t)                                                      \
        {                                                                     \
            _Pragma("unroll")                                                 \
            for (int j = 0; j < 4; j++)                                       \
                GLOAD_LDS16(ssrc[j] + (t) * (32 * NK), sdst[j] + (bb) * 8192);\
        }

    STAGE(0, 0)
    STAGE(1, 1)

    const int sw = row & 7;
    float l = 0.f, G = 0.f;

    #pragma unroll
    for (int t = 0; t < NTILES; t++) {            // fully unrolled: buf static
        if (t + 1 < NTILES) { WAITVM4; } else { WAITVM0; }
        __builtin_amdgcn_s_barrier();
        if (t + 2 < NTILES) STAGE((t + 2) % 3, t + 2)

        const unsigned short* bs = xsa + (t % 3) * 8192 + row * NK;
        f32x16 sa = {}, ga = {};
        #pragma unroll
        for (int kk = 0; kk < 16; kk++) {
            int ch = 2 * kk + bh;                 // logical 16B chunk
            int ph = (ch & ~7) | ((ch & 7) ^ sw); // swizzled (low 3 bits)
            bf16x8 a = *(const bf16x8*)(bs + ph * 8);
            sa = __builtin_amdgcn_mfma_f32_32x32x16_bf16(a, uf[kk], sa, 0, 0, 0);
            ga = __builtin_amdgcn_mfma_f32_32x32x16_bf16(a, ff[kk], ga, 0, 0, 0);
        }

        // max-free softmax accumulation (rows fully in-register)
        #pragma unroll
        for (int r = 0; r < 16; r++) {
            float e = __builtin_amdgcn_exp2f(sa[r]);
            l += e;
            G += e * ga[r];
        }
    }

    // rows split across lane-halves only: one xor-32 finishes the s-reduce
    l += __shfl_xor(l, 32);
    G += __shfl_xor(G, 32);
    if (lane < 32) {
        size_t idx = ((size_t)b * SSPLIT + sp) * NC + c0 + lane;
        pl[idx] = l; pg[idx] = G;
    }
}

// -------- combine S-split partials + bias -> y [b][c] ----------------------
__global__ __launch_bounds__(256) void combine_kernel(
    const float* __restrict__ pl, const float* __restrict__ pg,
    const float* __restrict__ fb, float* __restrict__ out)
{
    int idx = blockIdx.x * 256 + threadIdx.x;     // over B*NC
    if (idx >= B * NC) return;
    int b = idx / NC, c = idx % NC;
    float l = 0.f, g = 0.f;
    #pragma unroll
    for (int sp = 0; sp < SSPLIT; sp++) {
        size_t i = ((size_t)b * SSPLIT + sp) * NC + c;
        l += pl[i];
        g += pg[i];
    }
    out[idx] = g / l + fb[c];
}

extern "C" void kernel_launch(void* const* d_in, const int* in_sizes, int n_in,
                              void* d_out, int out_size, void* d_ws, size_t ws_size,
                              hipStream_t stream) {
    const int*   text   = (const int*)  d_in[0];
    const float* emb    = (const float*)d_in[1];
    const float* conv_w = (const float*)d_in[2];
    const float* conv_b = (const float*)d_in[3];
    const float* U_w    = (const float*)d_in[4];
    const float* F_w    = (const float*)d_in[5];
    const float* f_b    = (const float*)d_in[6];
    float* out = (float*)d_out;

    char* ws = (char*)d_ws;
    unsigned short* xf  = (unsigned short*)ws; ws += (size_t)B * S * NK * 2;
    unsigned short* wtb = (unsigned short*)ws; ws += (size_t)KSZ * NK * D_MODEL * 2;
    unsigned short* Ub  = (unsigned short*)ws; ws += (size_t)NC * NK * 2;
    unsigned short* Fb  = (unsigned short*)ws; ws += (size_t)NC * NK * 2;
    float* pl = (float*)ws; ws += (size_t)SSPLIT * B * NC * 4;
    float* pg = (float*)ws; ws += (size_t)SSPLIT * B * NC * 4;

    prep_all<<<dim3((PREP_N + 255) / 256), 256, 0, stream>>>(conv_w, wtb, U_w, Ub, F_w, Fb);
    conv_mfma<<<dim3(B * S / CM), 512, 0, stream>>>(text, emb, wtb, conv_b, xf);
    attn_mfma<<<dim3(NC / 128, SSPLIT, B), 256, 0, stream>>>(xf, Ub, Fb, pl, pg);
    combine_kernel<<<dim3((B * NC + 255) / 256), 256, 0, stream>>>(pl, pg, f_b, out);
}

// Round 12
// 218.358 us; speedup vs baseline: 1.1003x; 1.1003x over previous
//
#include <hip/hip_runtime.h>
#include <math.h>

#define B 8
#define S 2048
#define D_MODEL 512
#define NK 256      // n_kernels (conv out channels / attention feature dim)
#define KSZ 9
#define NC 4096     // n_classes
#define PADW 4
#define SSPLIT 4    // attention s-dimension split
#define CM 64       // conv s-rows per block (r11's CM=32 regressed: broke depth-3 latency cover)
#define CW (CM + 8) // staged window rows (72)
#define NSTG (KSZ * 16)                // 144 K-stages: stg = t*16 + h (h = 32-d chunk)
#define NTILES ((S / SSPLIT) / 32)     // 16 x-tiles per attn block

typedef __attribute__((ext_vector_type(8))) short bf16x8;
typedef __attribute__((ext_vector_type(4))) float f32x4;
typedef __attribute__((ext_vector_type(16))) float f32x16;

static __device__ __forceinline__ unsigned short f2bf(float f) {
    unsigned int u = __float_as_uint(f);
    unsigned int r = (u + 0x7fffu + ((u >> 16) & 1u)) >> 16;
    return (unsigned short)r;
}

#define GLOAD_LDS16(g, l) __builtin_amdgcn_global_load_lds( \
    (const __attribute__((address_space(1))) void*)(g),     \
    (__attribute__((address_space(3))) void*)(l), 16, 0, 0)

// ---- fused prep: conv_w -> wtb [stg][k][d32] bf16 (stage-contig 16KB);
// ---- U (pre-scaled by log2e) / F fp32 -> bf16, 4 elems/thread vectorized --
#define PREP_W (KSZ * NK * D_MODEL)
#define PREP_UF (NC * NK)
#define PREP_N (PREP_W + (2 * PREP_UF) / 4)
__global__ __launch_bounds__(256) void prep_all(
    const float* __restrict__ w, unsigned short* __restrict__ wtb,
    const float* __restrict__ U, unsigned short* __restrict__ Ub,
    const float* __restrict__ F, unsigned short* __restrict__ Fb)
{
    const float LOG2E = 1.44269504088896340736f;
    int idx = blockIdx.x * 256 + threadIdx.x;
    if (idx < PREP_W) {
        int dd  = idx & 31;
        int k   = (idx >> 5) & (NK - 1);
        int stg = idx >> 13;              // / (32*NK)
        int t = stg >> 4, h = stg & 15;
        wtb[idx] = f2bf(w[((size_t)k * D_MODEL + h * 32 + dd) * KSZ + t]);
        return;
    }
    idx -= PREP_W;
    if (idx < PREP_UF / 4) {
        float4 v = ((const float4*)U)[idx];
        ushort4 o;
        o.x = f2bf(v.x * LOG2E); o.y = f2bf(v.y * LOG2E);
        o.z = f2bf(v.z * LOG2E); o.w = f2bf(v.w * LOG2E);
        ((ushort4*)Ub)[idx] = o;
        return;
    }
    idx -= PREP_UF / 4;
    if (idx < PREP_UF / 4) {
        float4 v = ((const float4*)F)[idx];
        ushort4 o;
        o.x = f2bf(v.x); o.y = f2bf(v.y);
        o.z = f2bf(v.z); o.w = f2bf(v.w);
        ((ushort4*)Fb)[idx] = o;
    }
}

// ---- embed-gather + MFMA conv1d + bias + tanh -> xf bf16 [b][s][k] --------
// r11 post-mortem: CM=32 regressed conv 62->87us (MfmaUtil 17.7): the K-loop
// is L2-LATENCY-bound on the wtb stream; depth-3 covers ~200cyc only with
// 8 MFMA/stage. Halving M halved the cover. Revert CM=64.
// r12 (this): channel-split twin blocks — 256 threads (4 waves), half the
// channels each (n0 = half*128 + wv*32); per-wave K-loop (32 ch, 4 A-frags,
// depth-3, 8 MFMA/stage) BYTE-IDENTICAL to the r8-proven optimum. Grid 512
// = 2 blocks/CU (LDS 2x73.7KB = 147 <= 160). Twin (i, i+256) shares b,s0 and
// lands on the same XCD (256%8==0): duplicated staging is L2-hot, and one
// block's K-loop overlaps the other's staging + L2 stalls (two independent
// barrier groups per CU instead of one CU-wide barrier at 1 block/CU).
__global__ __launch_bounds__(256, 2) void conv_mfma(
    const int* __restrict__ text, const float* __restrict__ emb,
    const unsigned short* __restrict__ wtb, const float* __restrict__ bias,
    unsigned short* __restrict__ xf)
{
    __shared__ unsigned short xs[CW * D_MODEL];   // 73,728 B
    const int half = blockIdx.x >> 8;             // channel half (twin = +256)
    const int rem  = blockIdx.x & 255;
    const int b  = rem >> 5;                      // S/CM = 32 s-blocks
    const int s0 = (rem & 31) * CM;
    const int tid = threadIdx.x;

    for (int u = tid; u < CW * 64; u += 256) {    // 4608 units = 18 iters
        int row = u >> 6, c = u & 63;             // c = logical 16B chunk
        int gs = s0 + row - PADW;
        float4 v0 = make_float4(0.f, 0.f, 0.f, 0.f), v1 = v0;
        if (gs >= 0 && gs < S) {
            int tok = text[b * S + gs];
            const float4* e4 = (const float4*)(emb + (size_t)tok * D_MODEL + c * 8);
            v0 = e4[0]; v1 = e4[1];
        }
        union { bf16x8 v; unsigned short us[8]; } pk;
        pk.us[0] = f2bf(v0.x); pk.us[1] = f2bf(v0.y);
        pk.us[2] = f2bf(v0.z); pk.us[3] = f2bf(v0.w);
        pk.us[4] = f2bf(v1.x); pk.us[5] = f2bf(v1.y);
        pk.us[6] = f2bf(v1.z); pk.us[7] = f2bf(v1.w);
        int phys = c ^ (row & 7);
        *(bf16x8*)(xs + row * D_MODEL + phys * 8) = pk.v;
    }
    __syncthreads();                              // the ONLY barrier

    const int wv   = tid >> 6;                    // 0..3
    const int lane = tid & 63;
    const int cl   = lane & 15;
    const int quad = lane >> 4;
    const int n0   = half * 128 + wv * 32;        // 4 waves cover 128 channels

    bf16x8 A0[4], A1[4], A2[4], B0[2], B1[2], B2[2];
    f32x4 acc[4][2] = {};

    #define LDB(BB, stg)                                                      \
        {                                                                     \
            const unsigned short* wp = wtb + (size_t)(stg) * (NK * 32)        \
                                       + (n0 + cl) * 32 + quad * 8;           \
            BB[0] = *(const bf16x8*)(wp);                                     \
            BB[1] = *(const bf16x8*)(wp + 16 * 32);                           \
        }
    #define LDA(AA, stg)                                                      \
        {                                                                     \
            int t_ = (stg) >> 4, h_ = (stg) & 15;                             \
            _Pragma("unroll")                                                 \
            for (int ms = 0; ms < 4; ms++) {                                  \
                int row = cl + ms * 16 + t_;                                  \
                int ph  = (h_ * 4 + quad) ^ (row & 7);                        \
                AA[ms] = *(const bf16x8*)(xs + row * D_MODEL + ph * 8);       \
            }                                                                 \
        }
    #define FENCE asm volatile("" ::: "memory");
    #define DOMFMA(AA, BB)                                                    \
        _Pragma("unroll")                                                     \
        for (int ms = 0; ms < 4; ms++) {                                      \
            acc[ms][0] = __builtin_amdgcn_mfma_f32_16x16x32_bf16(AA[ms], BB[0], acc[ms][0], 0, 0, 0); \
            acc[ms][1] = __builtin_amdgcn_mfma_f32_16x16x32_bf16(AA[ms], BB[1], acc[ms][1], 0, 0, 0); \
        }

    LDB(B0, 0) LDA(A0, 0) LDB(B1, 1) LDA(A1, 1) LDB(B2, 2) LDA(A2, 2) FENCE

    for (int ss = 0; ss < NSTG; ss += 3) {        // 48 iters
        DOMFMA(A0, B0)
        if (ss + 3 < NSTG) { LDB(B0, ss + 3) LDA(A0, ss + 3) FENCE }
        DOMFMA(A1, B1)
        if (ss + 4 < NSTG) { LDB(B1, ss + 4) LDA(A1, ss + 4) FENCE }
        DOMFMA(A2, B2)
        if (ss + 5 < NSTG) { LDB(B2, ss + 5) LDA(A2, ss + 5) FENCE }
    }

    #pragma unroll
    for (int ns = 0; ns < 2; ns++) {
        const int k = n0 + ns * 16 + cl;
        const float bk = bias[k];
        #pragma unroll
        for (int ms = 0; ms < 4; ms++) {
            #pragma unroll
            for (int r = 0; r < 4; r++) {
                int s = s0 + ms * 16 + quad * 4 + r;
                float v = acc[ms][ns][r] + bk;
                float e = __expf(2.f * v);
                float th = 1.f - 2.f / (e + 1.f); // tanh(v)
                xf[((size_t)b * S + s) * NK + k] = f2bf(th);
            }
        }
    }
}

// -------- MFMA attention: max-free softmax, bf16 U/F tables ----------------
// r10 result: 32x32x16 halved bank conflicts (8.4M->4.2M) and VALU (25->17)
// but dur flat at ~68us = 40% of dense peak — the documented plateau for
// non-8-phase structures. attn considered locally converged; kept as-is.
#define WAITVM4 asm volatile("s_waitcnt vmcnt(4)" ::: "memory")
#define WAITVM0 asm volatile("s_waitcnt vmcnt(0)" ::: "memory")
__global__ __launch_bounds__(256, 2) void attn_mfma(
    const unsigned short* __restrict__ xf, const unsigned short* __restrict__ Ub,
    const unsigned short* __restrict__ Fb, float* __restrict__ pl,
    float* __restrict__ pg)
{
    __shared__ unsigned short xsa[3 * 32 * NK];   // 3 x 16 KB
    const int b    = blockIdx.z;
    const int sp   = blockIdx.y;
    const int tid  = threadIdx.x;
    const int wv   = tid >> 6;
    const int lane = tid & 63;
    const int row  = lane & 31;                   // A s-row / B class row
    const int bh   = lane >> 5;                   // k-half selector
    const int c0   = blockIdx.x * 128 + wv * 32;  // 32 classes per wave
    const int wvu  = __builtin_amdgcn_readfirstlane(wv);

    // B tables: class = lane&31, k = bh*8 + kk*16 .. +8  (16 slices)
    bf16x8 uf[16], ff[16];
    {
        const unsigned short* up = Ub + (size_t)(c0 + row) * NK + bh * 8;
        const unsigned short* fp = Fb + (size_t)(c0 + row) * NK + bh * 8;
        #pragma unroll
        for (int kk = 0; kk < 16; kk++) {
            uf[kk] = *(const bf16x8*)(up + kk * 16);
            ff[kk] = *(const bf16x8*)(fp + kk * 16);
        }
    }

    const int sbeg = sp * (S / SSPLIT);
    const unsigned short* xb = xf + ((size_t)b * S + sbeg) * NK;

    // hoisted staging pointers (loop-invariant; only t*32*NK varies)
    const unsigned short* ssrc[4];
    unsigned short* sdst[4];
    #pragma unroll
    for (int j = 0; j < 4; j++) {
        int C = j * 256 + tid;
        int r = C >> 5, p = C & 31;
        int jl = p ^ (r & 7);
        ssrc[j] = xb + (size_t)r * NK + jl * 8;
        sdst[j] = xsa + j * 2048 + wvu * 512;
    }

    #define STAGE(bb, t)                                                      \
        {                                                                     \
            _Pragma("unroll")                                                 \
            for (int j = 0; j < 4; j++)                                       \
                GLOAD_LDS16(ssrc[j] + (t) * (32 * NK), sdst[j] + (bb) * 8192);\
        }

    STAGE(0, 0)
    STAGE(1, 1)

    const int sw = row & 7;
    float l = 0.f, G = 0.f;

    #pragma unroll
    for (int t = 0; t < NTILES; t++) {            // fully unrolled: buf static
        if (t + 1 < NTILES) { WAITVM4; } else { WAITVM0; }
        __builtin_amdgcn_s_barrier();
        if (t + 2 < NTILES) STAGE((t + 2) % 3, t + 2)

        const unsigned short* bs = xsa + (t % 3) * 8192 + row * NK;
        f32x16 sa = {}, ga = {};
        #pragma unroll
        for (int kk = 0; kk < 16; kk++) {
            int ch = 2 * kk + bh;                 // logical 16B chunk
            int ph = (ch & ~7) | ((ch & 7) ^ sw); // swizzled (low 3 bits)
            bf16x8 a = *(const bf16x8*)(bs + ph * 8);
            sa = __builtin_amdgcn_mfma_f32_32x32x16_bf16(a, uf[kk], sa, 0, 0, 0);
            ga = __builtin_amdgcn_mfma_f32_32x32x16_bf16(a, ff[kk], ga, 0, 0, 0);
        }

        // max-free softmax accumulation (rows fully in-register)
        #pragma unroll
        for (int r = 0; r < 16; r++) {
            float e = __builtin_amdgcn_exp2f(sa[r]);
            l += e;
            G += e * ga[r];
        }
    }

    // rows split across lane-halves only: one xor-32 finishes the s-reduce
    l += __shfl_xor(l, 32);
    G += __shfl_xor(G, 32);
    if (lane < 32) {
        size_t idx = ((size_t)b * SSPLIT + sp) * NC + c0 + lane;
        pl[idx] = l; pg[idx] = G;
    }
}

// -------- combine S-split partials + bias -> y [b][c] ----------------------
__global__ __launch_bounds__(256) void combine_kernel(
    const float* __restrict__ pl, const float* __restrict__ pg,
    const float* __restrict__ fb, float* __restrict__ out)
{
    int idx = blockIdx.x * 256 + threadIdx.x;     // over B*NC
    if (idx >= B * NC) return;
    int b = idx / NC, c = idx % NC;
    float l = 0.f, g = 0.f;
    #pragma unroll
    for (int sp = 0; sp < SSPLIT; sp++) {
        size_t i = ((size_t)b * SSPLIT + sp) * NC + c;
        l += pl[i];
        g += pg[i];
    }
    out[idx] = g / l + fb[c];
}

extern "C" void kernel_launch(void* const* d_in, const int* in_sizes, int n_in,
                              void* d_out, int out_size, void* d_ws, size_t ws_size,
                              hipStream_t stream) {
    const int*   text   = (const int*)  d_in[0];
    const float* emb    = (const float*)d_in[1];
    const float* conv_w = (const float*)d_in[2];
    const float* conv_b = (const float*)d_in[3];
    const float* U_w    = (const float*)d_in[4];
    const float* F_w    = (const float*)d_in[5];
    const float* f_b    = (const float*)d_in[6];
    float* out = (float*)d_out;

    char* ws = (char*)d_ws;
    unsigned short* xf  = (unsigned short*)ws; ws += (size_t)B * S * NK * 2;
    unsigned short* wtb = (unsigned short*)ws; ws += (size_t)KSZ * NK * D_MODEL * 2;
    unsigned short* Ub  = (unsigned short*)ws; ws += (size_t)NC * NK * 2;
    unsigned short* Fb  = (unsigned short*)ws; ws += (size_t)NC * NK * 2;
    float* pl = (float*)ws; ws += (size_t)SSPLIT * B * NC * 4;
    float* pg = (float*)ws; ws += (size_t)SSPLIT * B * NC * 4;

    prep_all<<<dim3((PREP_N + 255) / 256), 256, 0, stream>>>(conv_w, wtb, U_w, Ub, F_w, Fb);
    conv_mfma<<<dim3(2 * B * S / CM), 256, 0, stream>>>(text, emb, wtb, conv_b, xf);
    attn_mfma<<<dim3(NC / 128, SSPLIT, B), 256, 0, stream>>>(xf, Ub, Fb, pl, pg);
    combine_kernel<<<dim3((B * NC + 255) / 256), 256, 0, stream>>>(pl, pg, f_b, out);
}